// Round 1
// baseline (880.622 us; speedup 1.0000x reference)
//
#include <hip/hip_runtime.h>
#include <hip/hip_bf16.h>

// SDE Euler-Maruyama: x_{k+1} = x_k + dt*(x_k @ A^T) + (sigma*sqrt(dt))*dW_k
// out[0] = x0, out[k+1] = x_{k+1}, out shape [1001, 1024, 256].
//
// Strategy: paths independent -> 256 blocks x 4 paths. bf16 MFMA 16x16x32
// (M=16 padded, 4 real paths; garbage rows read duplicated real rows, outputs
// of garbage rows never stored). A-matrix bf16 fragments live in registers
// (128 VGPR/wave, wave owns a 64-output-column slice), loaded once.
// x state fp32 in registers (thread owns path w, dims 4l..4l+3), round-trips
// per step through swizzled LDS as bf16 for fragment loads.

typedef __attribute__((ext_vector_type(4))) float fvec4;
typedef __attribute__((ext_vector_type(4))) unsigned short usvec4;
typedef __attribute__((ext_vector_type(8))) short svec8;
typedef __attribute__((ext_vector_type(4))) float f32x4;

constexpr int D = 256;
constexpr int BATCH = 1024;
constexpr int NSTEPS = 1000;
constexpr float DT = 0.001f;
constexpr float SQRT_DT = 0.03162277660168379f;  // sqrt(0.001)

__device__ __forceinline__ unsigned short f2bf(float f) {
  // round-to-nearest-even f32 -> bf16 (inputs are well-behaved, no NaN care)
  unsigned int u = __float_as_uint(f);
  u += 0x7FFFu + ((u >> 16) & 1u);
  return (unsigned short)(u >> 16);
}

__global__ __launch_bounds__(256, 1)
void sde_em_kernel(const float* __restrict__ x0, const float* __restrict__ Amat,
                   const float* __restrict__ sigma, const float* __restrict__ dW,
                   float* __restrict__ out) {
  // xb: bf16 x tile, 4 rows (paths) x 256 cols, XOR-swizzled (byte ^= row<<6)
  __shared__ __align__(16) unsigned short xb[4 * 256];
  // dr: fp32 drift tile, 4 rows x 256 cols
  __shared__ __align__(16) float dr[4 * 256];

  const int t = threadIdx.x;
  const int w = t >> 6;          // wave id: path-row (update role) / N-slice (mfma role)
  const int l = t & 63;
  const int d4 = l << 2;         // this thread's 4 dims
  const int p = (blockIdx.x << 2) + w;  // this thread's path

  // ---- one-time: A fragments (GEMM B-operand) into registers, bf16 ----
  // drift[m][n] = sum_k x[m][k] * A[n][k]  ->  Bfrag[k][n] = A[n][k]
  // B-frag layout (16x16x32): lane holds col n = l&15, k = (l>>4)*8 + i
  svec8 bfr[4][8];
  {
    const int nbase = (w << 6) + (l & 15);   // + tt*16
    const int kb = (l >> 4) << 3;            // + kt*32
#pragma unroll
    for (int tt = 0; tt < 4; ++tt) {
#pragma unroll
      for (int kt = 0; kt < 8; ++kt) {
        const float* src = Amat + (size_t)(nbase + (tt << 4)) * D + (kt << 5) + kb;
        fvec4 a0 = *(const fvec4*)(src);
        fvec4 a1 = *(const fvec4*)(src + 4);
        svec8 b;
        b[0] = (short)f2bf(a0[0]); b[1] = (short)f2bf(a0[1]);
        b[2] = (short)f2bf(a0[2]); b[3] = (short)f2bf(a0[3]);
        b[4] = (short)f2bf(a1[0]); b[5] = (short)f2bf(a1[1]);
        b[6] = (short)f2bf(a1[2]); b[7] = (short)f2bf(a1[3]);
        bfr[tt][kt] = b;
      }
    }
  }

  // ---- per-thread state ----
  fvec4 sig = *(const fvec4*)(sigma + d4);
  sig *= SQRT_DT;
  fvec4 x = *(const fvec4*)(x0 + (size_t)p * D + d4);

  // out[0] = x0 (exact copy)
  *(fvec4*)(out + (size_t)p * D + d4) = x;

  // seed xb with bf16(x0); swizzle in ushort units: idx = row*256 + (l*4 ^ row*32)
  {
    usvec4 v = { f2bf(x[0]), f2bf(x[1]), f2bf(x[2]), f2bf(x[3]) };
    *(usvec4*)&xb[(w << 8) + ((l << 2) ^ (w << 5))] = v;
  }

  // prefetch dW[0]
  fvec4 dwc = *(const fvec4*)(dW + (size_t)p * D + d4);

  const int rr = l & 3;   // A-operand row: real row (l&15)&3 — garbage rows
  const int q  = l >> 4;  //   duplicate rows 0-3 (broadcast reads, harmless)

  __syncthreads();

  for (int n = 0; n < NSTEPS; ++n) {
    // prefetch next step's dW (latency hidden under MFMA phase)
    const int nn = (n < NSTEPS - 1) ? (n + 1) : n;
    fvec4 dwn = *(const fvec4*)(dW + (size_t)nn * (BATCH * D) + (size_t)p * D + d4);

    // ---- MFMA: drift for 4 paths x 64 cols per wave ----
    f32x4 acc[4];
#pragma unroll
    for (int tt = 0; tt < 4; ++tt) acc[tt] = (f32x4){0.f, 0.f, 0.f, 0.f};
#pragma unroll
    for (int kt = 0; kt < 8; ++kt) {
      // A-operand frag: lane row = l&15 -> serve (l&15)&3 = rr (rows duplicated)
      svec8 a = *(const svec8*)&xb[(rr << 8) + (((kt << 5) + (q << 3)) ^ (rr << 5))];
#pragma unroll
      for (int tt = 0; tt < 4; ++tt)
        acc[tt] = __builtin_amdgcn_mfma_f32_16x16x32_bf16(a, bfr[tt][kt], acc[tt], 0, 0, 0);
    }

    // C/D layout: col = lane&15, row = (lane>>4)*4 + reg. Real rows 0-3 live
    // entirely in lanes 0-15 (regs = path).
    if (l < 16) {
#pragma unroll
      for (int tt = 0; tt < 4; ++tt) {
#pragma unroll
        for (int r = 0; r < 4; ++r)
          dr[(r << 8) + (w << 6) + (tt << 4) + l] = acc[tt][r];
      }
    }
    __syncthreads();

    // ---- update (clean coalesced layout: thread = (path w, dims 4l..4l+3)) ----
    fvec4 df = *(const fvec4*)&dr[(w << 8) + d4];
    x[0] = __builtin_fmaf(DT, df[0], __builtin_fmaf(sig[0], dwc[0], x[0]));
    x[1] = __builtin_fmaf(DT, df[1], __builtin_fmaf(sig[1], dwc[1], x[1]));
    x[2] = __builtin_fmaf(DT, df[2], __builtin_fmaf(sig[2], dwc[2], x[2]));
    x[3] = __builtin_fmaf(DT, df[3], __builtin_fmaf(sig[3], dwc[3], x[3]));

    *(fvec4*)(out + (size_t)(n + 1) * (BATCH * D) + (size_t)p * D + d4) = x;

    usvec4 v = { f2bf(x[0]), f2bf(x[1]), f2bf(x[2]), f2bf(x[3]) };
    *(usvec4*)&xb[(w << 8) + ((l << 2) ^ (w << 5))] = v;

    dwc = dwn;
    __syncthreads();
  }
}

extern "C" void kernel_launch(void* const* d_in, const int* in_sizes, int n_in,
                              void* d_out, int out_size, void* d_ws, size_t ws_size,
                              hipStream_t stream) {
  const float* x0    = (const float*)d_in[0];
  const float* Amat  = (const float*)d_in[1];
  const float* sigma = (const float*)d_in[2];
  const float* dW    = (const float*)d_in[3];
  float* out = (float*)d_out;
  sde_em_kernel<<<dim3(256), dim3(256), 0, stream>>>(x0, Amat, sigma, dW, out);
}

// Round 2
// 849.294 us; speedup vs baseline: 1.0369x; 1.0369x over previous
//
#include <hip/hip_runtime.h>
#include <hip/hip_bf16.h>

// SDE Euler-Maruyama: x_{k+1} = x_k + dt*(x_k @ A^T) + (sigma*sqrt(dt))*dW_k
// out[0] = x0, out[k+1] = x_{k+1}, out shape [1001, 1024, 256].
//
// R1: 880us, latency-bound (HBM 21%, MfmaUtil 25%, 1 wave/SIMD).
// R2 change: in-loop __syncthreads() -> lgkmcnt(0)+raw s_barrier (no vmcnt
// drain: dW prefetch + out stores stay in flight across barriers), 2-deep
// dW prefetch, nontemporal dW/out.

typedef __attribute__((ext_vector_type(4))) float fvec4;
typedef __attribute__((ext_vector_type(4))) unsigned short usvec4;
typedef __attribute__((ext_vector_type(8))) short svec8;
typedef __attribute__((ext_vector_type(4))) float f32x4;

constexpr int D = 256;
constexpr int BATCH = 1024;
constexpr int NSTEPS = 1000;
constexpr float DT = 0.001f;
constexpr float SQRT_DT = 0.03162277660168379f;  // sqrt(0.001)

__device__ __forceinline__ unsigned short f2bf(float f) {
  // round-to-nearest-even f32 -> bf16
  unsigned int u = __float_as_uint(f);
  u += 0x7FFFu + ((u >> 16) & 1u);
  return (unsigned short)(u >> 16);
}

// Barrier that waits only on LDS ops: does NOT drain vmcnt (global loads and
// stores stay in flight). Cross-wave traffic in this kernel is LDS-only.
__device__ __forceinline__ void lds_barrier() {
  __builtin_amdgcn_sched_barrier(0);
  asm volatile("s_waitcnt lgkmcnt(0)" ::: "memory");
  __builtin_amdgcn_s_barrier();
  __builtin_amdgcn_sched_barrier(0);
}

__global__ __launch_bounds__(256, 1)
void sde_em_kernel(const float* __restrict__ x0, const float* __restrict__ Amat,
                   const float* __restrict__ sigma, const float* __restrict__ dW,
                   float* __restrict__ out) {
  // xb: bf16 x tile, 4 rows (paths) x 256 cols, XOR-swizzled (ushort idx ^= row*32)
  __shared__ __align__(16) unsigned short xb[4 * 256];
  // dr: fp32 drift tile, 4 rows x 256 cols
  __shared__ __align__(16) float dr[4 * 256];

  const int t = threadIdx.x;
  const int w = t >> 6;          // wave id: path-row (update role) / N-slice (mfma role)
  const int l = t & 63;
  const int d4 = l << 2;         // this thread's 4 dims
  const int p = (blockIdx.x << 2) + w;  // this thread's path

  // ---- one-time: A fragments (GEMM B-operand) into registers, bf16 ----
  // drift[m][n] = sum_k x[m][k] * A[n][k]  ->  Bfrag[k][n] = A[n][k]
  // B-frag layout (16x16x32): lane holds col n = l&15, k = (l>>4)*8 + i
  svec8 bfr[4][8];
  {
    const int nbase = (w << 6) + (l & 15);   // + tt*16
    const int kb = (l >> 4) << 3;            // + kt*32
#pragma unroll
    for (int tt = 0; tt < 4; ++tt) {
#pragma unroll
      for (int kt = 0; kt < 8; ++kt) {
        const float* src = Amat + (size_t)(nbase + (tt << 4)) * D + (kt << 5) + kb;
        fvec4 a0 = *(const fvec4*)(src);
        fvec4 a1 = *(const fvec4*)(src + 4);
        svec8 b;
        b[0] = (short)f2bf(a0[0]); b[1] = (short)f2bf(a0[1]);
        b[2] = (short)f2bf(a0[2]); b[3] = (short)f2bf(a0[3]);
        b[4] = (short)f2bf(a1[0]); b[5] = (short)f2bf(a1[1]);
        b[6] = (short)f2bf(a1[2]); b[7] = (short)f2bf(a1[3]);
        bfr[tt][kt] = b;
      }
    }
  }

  // ---- per-thread state ----
  fvec4 sig = *(const fvec4*)(sigma + d4);
  sig *= SQRT_DT;
  fvec4 x = *(const fvec4*)(x0 + (size_t)p * D + d4);

  // out[0] = x0 (exact copy)
  __builtin_nontemporal_store(x, (fvec4*)(out + (size_t)p * D + d4));

  // seed xb with bf16(x0); swizzle in ushort units: idx = row*256 + (l*4 ^ row*32)
  {
    usvec4 v = { f2bf(x[0]), f2bf(x[1]), f2bf(x[2]), f2bf(x[3]) };
    *(usvec4*)&xb[(w << 8) + ((l << 2) ^ (w << 5))] = v;
  }

  // 2-deep dW prefetch
  const float* dwp = dW + (size_t)p * D + d4;
  fvec4 dwc = __builtin_nontemporal_load((const fvec4*)(dwp));
  fvec4 dwb = __builtin_nontemporal_load((const fvec4*)(dwp + (size_t)(BATCH * D)));

  const int rr = l & 3;   // A-operand row: real row (l&15)&3 — garbage rows
  const int q  = l >> 4;  //   duplicate rows 0-3 (broadcast reads, harmless)

  __syncthreads();

  for (int n = 0; n < NSTEPS; ++n) {
    // prefetch dW for step n+2 (two full steps of cover; no vmcnt drain in loop)
    const int nn = (n + 2 < NSTEPS) ? (n + 2) : (NSTEPS - 1);
    fvec4 dwn = __builtin_nontemporal_load(
        (const fvec4*)(dwp + (size_t)nn * (BATCH * D)));

    // ---- MFMA: drift for 4 paths x 64 cols per wave ----
    f32x4 acc[4];
#pragma unroll
    for (int tt = 0; tt < 4; ++tt) acc[tt] = (f32x4){0.f, 0.f, 0.f, 0.f};
#pragma unroll
    for (int kt = 0; kt < 8; ++kt) {
      // A-operand frag: lane row = l&15 -> serve (l&15)&3 = rr (rows duplicated)
      svec8 a = *(const svec8*)&xb[(rr << 8) + (((kt << 5) + (q << 3)) ^ (rr << 5))];
#pragma unroll
      for (int tt = 0; tt < 4; ++tt)
        acc[tt] = __builtin_amdgcn_mfma_f32_16x16x32_bf16(a, bfr[tt][kt], acc[tt], 0, 0, 0);
    }

    // C/D layout: col = lane&15, row = (lane>>4)*4 + reg. Real rows 0-3 live
    // entirely in lanes 0-15 (regs = path).
    if (l < 16) {
#pragma unroll
      for (int tt = 0; tt < 4; ++tt) {
#pragma unroll
        for (int r = 0; r < 4; ++r)
          dr[(r << 8) + (w << 6) + (tt << 4) + l] = acc[tt][r];
      }
    }
    lds_barrier();  // dr complete; dW loads & out stores stay in flight

    // ---- update (clean coalesced layout: thread = (path w, dims 4l..4l+3)) ----
    fvec4 df = *(const fvec4*)&dr[(w << 8) + d4];
    x[0] = __builtin_fmaf(DT, df[0], __builtin_fmaf(sig[0], dwc[0], x[0]));
    x[1] = __builtin_fmaf(DT, df[1], __builtin_fmaf(sig[1], dwc[1], x[1]));
    x[2] = __builtin_fmaf(DT, df[2], __builtin_fmaf(sig[2], dwc[2], x[2]));
    x[3] = __builtin_fmaf(DT, df[3], __builtin_fmaf(sig[3], dwc[3], x[3]));

    __builtin_nontemporal_store(
        x, (fvec4*)(out + (size_t)(n + 1) * (BATCH * D) + (size_t)p * D + d4));

    usvec4 v = { f2bf(x[0]), f2bf(x[1]), f2bf(x[2]), f2bf(x[3]) };
    *(usvec4*)&xb[(w << 8) + ((l << 2) ^ (w << 5))] = v;

    dwc = dwb;
    dwb = dwn;
    lds_barrier();  // xb complete for next step's MFMA reads
  }
}

extern "C" void kernel_launch(void* const* d_in, const int* in_sizes, int n_in,
                              void* d_out, int out_size, void* d_ws, size_t ws_size,
                              hipStream_t stream) {
  const float* x0    = (const float*)d_in[0];
  const float* Amat  = (const float*)d_in[1];
  const float* sigma = (const float*)d_in[2];
  const float* dW    = (const float*)d_in[3];
  float* out = (float*)d_out;
  sde_em_kernel<<<dim3(256), dim3(256), 0, stream>>>(x0, Amat, sigma, dW, out);
}